// Round 12
// baseline (131.799 us; speedup 1.0000x reference)
//
#include <hip/hip_runtime.h>

#define N_NODES 100000
#define N_EDGES 6400000
#define D_IN 256
constexpr float NEG_SLOPE = 0.2f;

// logical output ranges (gather/reduce granularity)
#define NRANGES 32
#define RANGE 3125          // nodes per logical range
#define NG 16               // gather groups per range

// bucket segments (coarser, for store locality + short ballot loop)
#define NRSEG 16
#define SEGRANGE 6250       // nodes per segment-range
#define NCH 1280            // edge chunks (bucket blocks)
#define CHE 5000            // edges per chunk
#define CAP 416             // per-(chunk,seg) capacity; mean 312.5, ~6 sigma
#define HALFCAP 208
#define CPG 80              // chunks per gather group (NCH/NG)
#define PFLAT (CPG * HALFCAP)        // pair-index space per gather block (16640)
#define NB ((PFLAT + 1023) / 1024)   // 17 batches
#define ABLK 256
#define CBLK 1024
#define NODE_BLKS 6250      // 16 nodes per 256-thr block
#define FCHE 400000         // fallback scan chunk

// ws layout (floats):
// [0,2N) xl | [2N,4N) xr | [4N,+4.8M) partial [NRANGES*NG][RANGE*3]
// then recs [NCH*NRSEG][CAP] float2 | counts [NCH*NRSEG] int | flag int

// ---------------- wave-aggregated LDS slot allocator ----------------
__device__ __forceinline__ int alloc_slot(int r, int* __restrict__ cnt) {
    const int lane = threadIdx.x & 63;
    const unsigned long long lt = (1ull << lane) - 1ull;
    int slot = 0;
    #pragma unroll
    for (int rr = 0; rr < NRSEG; ++rr) {
        const unsigned long long m = __ballot(r == rr);
        if (r == rr) {
            const int before = __popcll(m & lt);
            const int leader = __ffsll((unsigned long long)m) - 1;
            int base = 0;
            if (lane == leader) base = atomicAdd(&cnt[rr], __popcll(m));
            base = __shfl(base, leader);
            slot = base + before;
        }
    }
    return slot;
}

__device__ __forceinline__ void bucket_one(int src, int tgt, float ea,
                                           float2* __restrict__ recs,
                                           int* __restrict__ cnt, int c) {
    const int r  = tgt / SEGRANGE;
    const int li = tgt - r * SEGRANGE;        // < 6250 (13 bits)
    const int slot = alloc_slot(r, cnt);
    if (slot < CAP) {
        float2 rec;
        rec.x = __uint_as_float((unsigned)src | ((unsigned)li << 17));
        rec.y = ea;
        recs[(size_t)(c * NRSEG + r) * CAP + slot] = rec;
    }
}

template <bool IS64>
__device__ __forceinline__ void bucket_loop(const void* __restrict__ ei,
                                            const float* __restrict__ eattr,
                                            float2* __restrict__ recs,
                                            int* __restrict__ cnt, int c) {
    const int base = c * CHE;
    const int end  = base + CHE;
    for (int j = 0; j < CHE; j += ABLK * 4) {
        const int e0 = base + j + (int)threadIdx.x * 4;
        if (e0 + 4 <= end) {
            int4 sv, tv;
            if (IS64) {
                const int4* ps = (const int4*)((const long long*)ei + e0);
                int4 a = ps[0], b = ps[1];
                sv = make_int4(a.x, a.z, b.x, b.z);
                const int4* pt = (const int4*)((const long long*)ei + N_EDGES + e0);
                int4 cc = pt[0], dd = pt[1];
                tv = make_int4(cc.x, cc.z, dd.x, dd.z);
            } else {
                sv = *(const int4*)((const int*)ei + e0);
                tv = *(const int4*)((const int*)ei + N_EDGES + e0);
            }
            const float4 ev = *(const float4*)(eattr + e0);
            bucket_one(sv.x, tv.x, ev.x, recs, cnt, c);
            bucket_one(sv.y, tv.y, ev.y, recs, cnt, c);
            bucket_one(sv.z, tv.z, ev.z, recs, cnt, c);
            bucket_one(sv.w, tv.w, ev.w, recs, cnt, c);
        } else if (e0 < end) {
            for (int e = e0; e < end && e < e0 + 4; ++e) {
                int src, tgt;
                if (IS64) { src = (int)((const long long*)ei)[e]; tgt = (int)((const long long*)ei)[N_EDGES + e]; }
                else      { src = ((const int*)ei)[e];            tgt = ((const int*)ei)[N_EDGES + e]; }
                bucket_one(src, tgt, eattr[e], recs, cnt, c);
            }
        }
    }
}

__device__ __forceinline__ void node_body(const float* __restrict__ x,
                                          const float* __restrict__ Wl, const float* __restrict__ bl,
                                          const float* __restrict__ Wr, const float* __restrict__ br,
                                          float* __restrict__ xl, float* __restrict__ xr, int bid) {
    const int w    = bid * 4 + ((int)threadIdx.x >> 6);
    const int lane = threadIdx.x & 63;
    const int sub  = lane >> 4;
    const int l16  = lane & 15;
    const int n    = w * 4 + sub;             // < 100000 exactly
    float sl0 = 0.f, sl1 = 0.f, sr0 = 0.f, sr1 = 0.f;
    #pragma unroll
    for (int q = 0; q < 4; ++q) {
        const int k = q * 64 + l16 * 4;
        const float4 xv  = *(const float4*)(x + (size_t)n * D_IN + k);
        const float4 wlA = *(const float4*)(Wl + 2 * k);
        const float4 wlB = *(const float4*)(Wl + 2 * k + 4);
        const float4 wrA = *(const float4*)(Wr + 2 * k);
        const float4 wrB = *(const float4*)(Wr + 2 * k + 4);
        sl0 += xv.x*wlA.x + xv.y*wlA.z + xv.z*wlB.x + xv.w*wlB.z;
        sl1 += xv.x*wlA.y + xv.y*wlA.w + xv.z*wlB.y + xv.w*wlB.w;
        sr0 += xv.x*wrA.x + xv.y*wrA.z + xv.z*wrB.x + xv.w*wrB.z;
        sr1 += xv.x*wrA.y + xv.y*wrA.w + xv.z*wrB.y + xv.w*wrB.w;
    }
    #pragma unroll
    for (int o = 8; o > 0; o >>= 1) {
        sl0 += __shfl_xor(sl0, o);
        sl1 += __shfl_xor(sl1, o);
        sr0 += __shfl_xor(sr0, o);
        sr1 += __shfl_xor(sr1, o);
    }
    if (l16 == 0) {
        xl[2*n]   = sl0 + bl[0];
        xl[2*n+1] = sl1 + bl[1];
        xr[2*n]   = sr0 + br[0];
        xr[2*n+1] = sr1 + br[1];
    }
}

// Fused: blocks [0,NCH) bucket edges; blocks [NCH, NCH+NODE_BLKS) transform nodes.
__global__ __launch_bounds__(ABLK) void fused_node_bucket(
        const float* __restrict__ x,
        const float* __restrict__ Wl, const float* __restrict__ bl,
        const float* __restrict__ Wr, const float* __restrict__ br,
        const void* __restrict__ ei, const float* __restrict__ eattr,
        float* __restrict__ xl, float* __restrict__ xr,
        float2* __restrict__ recs, int* __restrict__ counts) {
    if (blockIdx.x < NCH) {
        __shared__ int cnt[NRSEG];
        __shared__ int sflag;
        const int c = blockIdx.x;
        if (threadIdx.x < NRSEG) cnt[threadIdx.x] = 0;
        if (threadIdx.x < 64) {   // wave 0: self-detect int64 vs int32
            int v = ((const int*)ei)[2 * threadIdx.x + 1];
            unsigned long long nz = __ballot(v != 0);
            if (threadIdx.x == 0) sflag = (nz == 0ull) ? 1 : 0;
        }
        __syncthreads();
        if (sflag) bucket_loop<true >(ei, eattr, recs, cnt, c);
        else       bucket_loop<false>(ei, eattr, recs, cnt, c);
        __syncthreads();
        if (threadIdx.x < NRSEG) {
            int v = cnt[threadIdx.x];
            counts[c * NRSEG + threadIdx.x] = v < CAP ? v : CAP;
        }
    } else {
        node_body(x, Wl, bl, Wr, br, xl, xr, (int)blockIdx.x - NCH);
    }
}

// Gather: block (r16, h, g) reads seg (chunk,r16) records, filters to half h,
// claim/winner LDS accumulation (75 KB -> 2 blocks/CU), dumps partial.
__global__ __launch_bounds__(CBLK, 8) void gather_accum(
        const float2* __restrict__ recs, const int* __restrict__ counts,
        const float* __restrict__ xl, const float* __restrict__ xr,
        const float* __restrict__ We, const float* __restrict__ att,
        float* __restrict__ partial) {
    __shared__ float  acc[RANGE * 3];   // 37.5 KB
    __shared__ float2 xrs[RANGE];       // 25 KB
    __shared__ int    tag[RANGE];       // 12.5 KB
    __shared__ int    s_n[CPG];
    const int b      = blockIdx.x;
    const int r16    = b & 15;
    const int h      = (b >> 4) & 1;
    const int g      = b >> 5;
    const int rr     = r16 * 2 + h;
    const int lo     = rr * RANGE;
    const int liBase = h * RANGE;
    for (int i = threadIdx.x; i < RANGE * 3; i += CBLK) acc[i] = 0.f;
    for (int i = threadIdx.x; i < RANGE; i += CBLK) xrs[i] = ((const float2*)xr)[lo + i];
    for (int i = threadIdx.x; i < CPG; i += CBLK) s_n[i] = counts[(g * CPG + i) * NRSEG + r16];
    __syncthreads();
    const float we0 = We[0], we1 = We[1];
    const float a0 = att[0], a1 = att[1];
    const float2* xl2 = (const float2*)xl;
    const int c0 = g * CPG;
    const int tid = threadIdx.x;

    // vm bit0/bit1: record exists (count) AND lands in this half-range
    auto fetch_pair = [&](int pidx, unsigned& vm) -> float4 {
        float4 out = make_float4(0.f, 0.f, 0.f, 0.f);
        vm = 0u;
        if (pidx < PFLAT) {
            const int cc = pidx / HALFCAP;
            const int i  = pidx - cc * HALFCAP;
            const int n  = s_n[cc];
            if (2 * i < n) {
                const float2* seg = recs + (size_t)((c0 + cc) * NRSEG + r16) * CAP;
                out = ((const float4*)seg)[i];
                unsigned v = 0u;
                if ((unsigned)((int)(__float_as_uint(out.x) >> 17) - liBase) < RANGE) v |= 1u;
                if ((2 * i + 1 < n) &&
                    (unsigned)((int)(__float_as_uint(out.z) >> 17) - liBase) < RANGE) v |= 2u;
                vm = v;
            }
        }
        return out;
    };

    unsigned vCur, vNxt, vFly;
    float4 curP = fetch_pair(tid, vCur);
    float4 nxtP = fetch_pair(CBLK + tid, vNxt);
    float2 xsA0 = make_float2(0.f, 0.f), xsA1 = make_float2(0.f, 0.f);
    if (vCur & 1u) xsA0 = xl2[__float_as_uint(curP.x) & 0x1FFFF];
    if (vCur & 2u) xsA1 = xl2[__float_as_uint(curP.z) & 0x1FFFF];

    bool d0 = false, d1 = false;
    int  dl0 = 0, dl1 = 0;
    float dc00 = 0.f, dc01 = 0.f, de0 = 0.f, dc10 = 0.f, dc11 = 0.f, de1 = 0.f;

    for (int bi = 0; bi < NB; ++bi) {
        float4 flyP = fetch_pair((bi + 2) * CBLK + tid, vFly);
        float2 xsB0 = make_float2(0.f, 0.f), xsB1 = make_float2(0.f, 0.f);
        if (vNxt & 1u) xsB0 = xl2[__float_as_uint(nxtP.x) & 0x1FFFF];
        if (vNxt & 2u) xsB1 = xl2[__float_as_uint(nxtP.z) & 0x1FFFF];

        // phase A: compute + claim; drain previous losers
        const bool h0 = (vCur & 1u) != 0u, h1 = (vCur & 2u) != 0u;
        int li0 = 0, li1 = 0;
        float ex0 = 0.f, cv00 = 0.f, cv01 = 0.f;
        float ex1 = 0.f, cv10 = 0.f, cv11 = 0.f;
        if (h0) {
            li0 = (int)(__float_as_uint(curP.x) >> 17) - liBase;
            const float2 xt = xrs[li0];
            float m0 = xsA0.x + xt.x + curP.y * we0;
            float m1 = xsA0.y + xt.y + curP.y * we1;
            m0 = m0 > 0.f ? m0 : NEG_SLOPE * m0;
            m1 = m1 > 0.f ? m1 : NEG_SLOPE * m1;
            ex0  = __expf(m0 * a0 + m1 * a1);
            cv00 = ex0 * xsA0.x;
            cv01 = ex0 * xsA0.y;
            tag[li0] = tid;
        }
        if (h1) {
            li1 = (int)(__float_as_uint(curP.z) >> 17) - liBase;
            const float2 xt = xrs[li1];
            float m0 = xsA1.x + xt.x + curP.w * we0;
            float m1 = xsA1.y + xt.y + curP.w * we1;
            m0 = m0 > 0.f ? m0 : NEG_SLOPE * m0;
            m1 = m1 > 0.f ? m1 : NEG_SLOPE * m1;
            ex1  = __expf(m0 * a0 + m1 * a1);
            cv10 = ex1 * xsA1.x;
            cv11 = ex1 * xsA1.y;
            tag[li1] = tid;
        }
        if (d0) {
            float* bp = acc + dl0 * 3;
            atomicAdd(bp + 0, dc00); atomicAdd(bp + 1, dc01); atomicAdd(bp + 2, de0);
            d0 = false;
        }
        if (d1) {
            float* bp = acc + dl1 * 3;
            atomicAdd(bp + 0, dc10); atomicAdd(bp + 1, dc11); atomicAdd(bp + 2, de1);
            d1 = false;
        }
        __syncthreads();
        // phase B: winners plain-RMW; losers deferred
        if (h0) {
            if (tag[li0] == tid) {
                float* bp = acc + li0 * 3;
                bp[0] += cv00; bp[1] += cv01; bp[2] += ex0;
            } else { d0 = true; dl0 = li0; dc00 = cv00; dc01 = cv01; de0 = ex0; }
        }
        if (h1) {
            if (tag[li1] == tid) {
                float* bp = acc + li1 * 3;
                bp[0] += cv10; bp[1] += cv11; bp[2] += ex1;
            } else { d1 = true; dl1 = li1; dc10 = cv10; dc11 = cv11; de1 = ex1; }
        }
        __syncthreads();
        curP = nxtP; vCur = vNxt; xsA0 = xsB0; xsA1 = xsB1;
        nxtP = flyP; vNxt = vFly;
    }
    if (d0) {
        float* bp = acc + dl0 * 3;
        atomicAdd(bp + 0, dc00); atomicAdd(bp + 1, dc01); atomicAdd(bp + 2, de0);
    }
    if (d1) {
        float* bp = acc + dl1 * 3;
        atomicAdd(bp + 0, dc10); atomicAdd(bp + 1, dc11); atomicAdd(bp + 2, de1);
    }
    __syncthreads();

    float* dst = partial + (size_t)(rr * NG + g) * (RANGE * 3);
    for (int i = threadIdx.x; i < RANGE * 3; i += CBLK) dst[i] = acc[i];
}

// Sum the NG partials per node, normalize, add bias.
__global__ void reduce_partials(const float* __restrict__ partial,
                                const float* __restrict__ bias, float* __restrict__ out) {
    int i = blockIdx.x * blockDim.x + threadIdx.x;
    if (i >= N_NODES) return;
    const int r = i / RANGE;
    const int li = i - r * RANGE;
    float n0 = 0.f, n1 = 0.f, d = 0.f;
    #pragma unroll 4
    for (int g = 0; g < NG; ++g) {
        const float* p = partial + (size_t)(r * NG + g) * (RANGE * 3) + (size_t)li * 3;
        n0 += p[0]; n1 += p[1]; d += p[2];
    }
    d += 1e-16f;
    float2 o;
    o.x = n0 / d + bias[0];
    o.y = n1 / d + bias[1];
    ((float2*)out)[i] = o;
}

// ---------------- fallbacks (small ws) ----------------
__global__ __launch_bounds__(ABLK) void node_only(const float* __restrict__ x,
                                                  const float* __restrict__ Wl, const float* __restrict__ bl,
                                                  const float* __restrict__ Wr, const float* __restrict__ br,
                                                  float* __restrict__ xl, float* __restrict__ xr) {
    node_body(x, Wl, bl, Wr, br, xl, xr, (int)blockIdx.x);
}

__global__ void detect_dtype(const int* __restrict__ ei32, int* __restrict__ flag) {
    int lane = threadIdx.x;
    int v = ei32[2 * lane + 1];
    unsigned long long nz = __ballot(v != 0);
    if (lane == 0) *flag = (nz == 0ull) ? 1 : 0;
}

template <bool IS64>
__device__ __forceinline__ void scan_loop(const void* __restrict__ ei,
                                          const float* __restrict__ eattr,
                                          const float2* __restrict__ xl2,
                                          const float2* __restrict__ xr2,
                                          float we0, float we1, float a0, float a1,
                                          int lo, int eBeg, int eEnd,
                                          float* __restrict__ acc) {
    for (int e = eBeg + (int)threadIdx.x; e < eEnd; e += CBLK) {
        int tgt;
        if (IS64) tgt = (int)((const long long*)ei)[N_EDGES + e];
        else      tgt = ((const int*)ei)[N_EDGES + e];
        unsigned li = (unsigned)(tgt - lo);
        if (li < RANGE) {
            int src;
            if (IS64) src = (int)((const long long*)ei)[e];
            else      src = ((const int*)ei)[e];
            const float ea = eattr[e];
            const float2 xs = xl2[src];
            const float2 xt = xr2[tgt];
            float m0 = xs.x + xt.x + ea * we0;
            float m1 = xs.y + xt.y + ea * we1;
            m0 = m0 > 0.f ? m0 : NEG_SLOPE * m0;
            m1 = m1 > 0.f ? m1 : NEG_SLOPE * m1;
            const float ex = __expf(m0 * a0 + m1 * a1);
            float* b = acc + li * 3u;
            atomicAdd(b + 0, ex * xs.x);
            atomicAdd(b + 1, ex * xs.y);
            atomicAdd(b + 2, ex);
        }
    }
}

__global__ __launch_bounds__(CBLK) void edge_scan(const void* __restrict__ ei,
                                                  const float* __restrict__ eattr,
                                                  const float* __restrict__ xl,
                                                  const float* __restrict__ xr,
                                                  const float* __restrict__ We,
                                                  const float* __restrict__ att,
                                                  float* __restrict__ partial,
                                                  const int* __restrict__ flag) {
    __shared__ float acc[RANGE * 3];
    const int r = blockIdx.x & (NRANGES - 1);
    const int g = blockIdx.x >> 5;
    for (int i = threadIdx.x; i < RANGE * 3; i += CBLK) acc[i] = 0.f;
    __syncthreads();
    const int lo = r * RANGE;
    const int eBeg = g * FCHE, eEnd = eBeg + FCHE;
    const float we0 = We[0], we1 = We[1];
    const float a0 = att[0], a1 = att[1];
    if (*flag)
        scan_loop<true >(ei, eattr, (const float2*)xl, (const float2*)xr, we0, we1, a0, a1, lo, eBeg, eEnd, acc);
    else
        scan_loop<false>(ei, eattr, (const float2*)xl, (const float2*)xr, we0, we1, a0, a1, lo, eBeg, eEnd, acc);
    __syncthreads();
    float* dst = partial + (size_t)(r * NG + g) * (RANGE * 3);
    for (int i = threadIdx.x; i < RANGE * 3; i += CBLK) dst[i] = acc[i];
}

__global__ void edge_pass_atomic(const void* __restrict__ ei,
                                 const float* __restrict__ eattr,
                                 const float* __restrict__ xl, const float* __restrict__ xr,
                                 const float* __restrict__ We, const float* __restrict__ att,
                                 float* __restrict__ acc4, const int* __restrict__ flag) {
    const int is64 = *flag;
    const float we0 = We[0], we1 = We[1];
    const float a0 = att[0], a1 = att[1];
    const int stride = gridDim.x * blockDim.x;
    for (int e = blockIdx.x * blockDim.x + threadIdx.x; e < N_EDGES; e += stride) {
        int src, tgt;
        if (is64) { src = (int)((const long long*)ei)[e]; tgt = (int)((const long long*)ei)[N_EDGES + e]; }
        else      { src = ((const int*)ei)[e];            tgt = ((const int*)ei)[N_EDGES + e]; }
        const float ea = eattr[e];
        const float2 xs = ((const float2*)xl)[src];
        const float2 xt = ((const float2*)xr)[tgt];
        float m0 = xs.x + xt.x + ea * we0;
        float m1 = xs.y + xt.y + ea * we1;
        m0 = m0 > 0.f ? m0 : NEG_SLOPE * m0;
        m1 = m1 > 0.f ? m1 : NEG_SLOPE * m1;
        const float ex = __expf(m0 * a0 + m1 * a1);
        float* b = acc4 + (size_t)tgt * 4;
        atomicAdd(b + 0, ex * xs.x);
        atomicAdd(b + 1, ex * xs.y);
        atomicAdd(b + 2, ex);
    }
}

__global__ void finalize4(const float* __restrict__ acc4,
                          const float* __restrict__ bias, float* __restrict__ out) {
    int i = blockIdx.x * blockDim.x + threadIdx.x;
    if (i >= N_NODES) return;
    const float4 a = ((const float4*)acc4)[i];
    const float d = a.z + 1e-16f;
    float2 o;
    o.x = a.x / d + bias[0];
    o.y = a.y / d + bias[1];
    ((float2*)out)[i] = o;
}
// -------------------------------------------------------

extern "C" void kernel_launch(void* const* d_in, const int* in_sizes, int n_in,
                              void* d_out, int out_size, void* d_ws, size_t ws_size,
                              hipStream_t stream) {
    const float* x    = (const float*)d_in[0];
    const void*  ei   = d_in[1];
    const float* ea   = (const float*)d_in[2];
    const float* Wl   = (const float*)d_in[3];
    const float* bl   = (const float*)d_in[4];
    const float* Wr   = (const float*)d_in[5];
    const float* br   = (const float*)d_in[6];
    const float* We   = (const float*)d_in[7];
    const float* att  = (const float*)d_in[8];
    const float* bias = (const float*)d_in[9];

    float* ws      = (float*)d_ws;
    float* xl      = ws;
    float* xr      = ws + 2 * N_NODES;
    float* partial = ws + 4 * N_NODES;
    const size_t partial_floats = (size_t)NRANGES * NG * RANGE * 3;
    float* recs_f  = partial + partial_floats;                 // [NCH*NRSEG][CAP] float2
    const size_t recs_floats = (size_t)NCH * NRSEG * CAP * 2;
    int*   counts  = (int*)(recs_f + recs_floats);             // [NCH*NRSEG]
    int*   flag    = counts + (size_t)NCH * NRSEG;

    const size_t need_bucket = (4 * (size_t)N_NODES + partial_floats + recs_floats
                                + (size_t)NCH * NRSEG + 16) * sizeof(float);
    const size_t need_scan   = (4 * (size_t)N_NODES + partial_floats + 16) * sizeof(float);

    if (ws_size >= need_bucket) {
        fused_node_bucket<<<NCH + NODE_BLKS, ABLK, 0, stream>>>(
            x, Wl, bl, Wr, br, ei, ea, xl, xr, (float2*)recs_f, counts);
        gather_accum<<<NRANGES * NG, CBLK, 0, stream>>>(
            (const float2*)recs_f, counts, xl, xr, We, att, partial);
        reduce_partials<<<(N_NODES + 255) / 256, 256, 0, stream>>>(partial, bias, (float*)d_out);
    } else if (ws_size >= need_scan) {
        int* f2 = (int*)(partial + partial_floats);
        node_only<<<NODE_BLKS, ABLK, 0, stream>>>(x, Wl, bl, Wr, br, xl, xr);
        detect_dtype<<<1, 64, 0, stream>>>((const int*)ei, f2);
        edge_scan<<<NRANGES * NG, CBLK, 0, stream>>>(ei, ea, xl, xr, We, att, partial, f2);
        reduce_partials<<<(N_NODES + 255) / 256, 256, 0, stream>>>(partial, bias, (float*)d_out);
    } else {
        float* acc4 = ws + 4 * N_NODES;
        int* f3 = (int*)(acc4 + 4 * (size_t)N_NODES);
        hipMemsetAsync(acc4, 0, (size_t)N_NODES * 4 * sizeof(float), stream);
        node_only<<<NODE_BLKS, ABLK, 0, stream>>>(x, Wl, bl, Wr, br, xl, xr);
        detect_dtype<<<1, 64, 0, stream>>>((const int*)ei, f3);
        edge_pass_atomic<<<4096, 256, 0, stream>>>(ei, ea, xl, xr, We, att, acc4, f3);
        finalize4<<<(N_NODES + 255) / 256, 256, 0, stream>>>(acc4, bias, (float*)d_out);
    }
}

// Round 13
// 99.161 us; speedup vs baseline: 1.3291x; 1.3291x over previous
//
#include <hip/hip_runtime.h>

#define N_NODES 100000
#define N_EDGES 6400000
#define D_IN 256
constexpr float NEG_SLOPE = 0.2f;

// logical output ranges (gather/reduce granularity)
#define NRANGES 32
#define RANGE 3125          // nodes per logical range
#define NG 16               // gather groups per range

// bucket segments (coarser: good store locality, 1 LDS atomic/edge)
#define NRSEG 16
#define SEGRANGE 6250       // nodes per segment-range
#define NCH 1280            // edge chunks (bucket blocks)
#define CHE 5000            // edges per chunk
#define CAP 416             // per-(chunk,seg) capacity; mean 312.5, ~6 sigma
#define HALFCAP 208
#define CPG 80              // chunks per gather group (NCH/NG)
#define PFLAT (CPG * HALFCAP)        // pair-index space per gather block (16640)
#define NB ((PFLAT + 1023) / 1024)   // 17 batches
#define ABLK 256
#define CBLK 1024
#define NODE_BLKS 6250      // 16 nodes per 256-thr block
#define FCHE 400000         // fallback scan chunk

// ws layout (floats):
// [0,2N) xl | [2N,4N) xr | [4N,+4.8M) partial [NRANGES*NG][RANGE*3]
// then recs [NCH*NRSEG][CAP] float2 | counts [NCH*NRSEG] int | flag int

// Plain per-lane slot allocation (LDS-atomic pipe ~4cy/lane is the known floor;
// ballot aggregation measured WORSE in r12: 16-iter loop -> VALUBusy 56%).
__device__ __forceinline__ void bucket_one(int src, int tgt, float ea,
                                           float2* __restrict__ recs,
                                           int* __restrict__ cnt, int c) {
    const int r  = tgt / SEGRANGE;
    const int li = tgt - r * SEGRANGE;        // < 6250 (13 bits)
    const int slot = atomicAdd(&cnt[r], 1);
    if (slot < CAP) {
        float2 rec;
        rec.x = __uint_as_float((unsigned)src | ((unsigned)li << 17));
        rec.y = ea;
        recs[(size_t)(c * NRSEG + r) * CAP + slot] = rec;
    }
}

template <bool IS64>
__device__ __forceinline__ void bucket_loop(const void* __restrict__ ei,
                                            const float* __restrict__ eattr,
                                            float2* __restrict__ recs,
                                            int* __restrict__ cnt, int c) {
    const int base = c * CHE;
    const int end  = base + CHE;
    for (int j = 0; j < CHE; j += ABLK * 4) {
        const int e0 = base + j + (int)threadIdx.x * 4;
        if (e0 + 4 <= end) {
            int4 sv, tv;
            if (IS64) {
                const int4* ps = (const int4*)((const long long*)ei + e0);
                int4 a = ps[0], b = ps[1];
                sv = make_int4(a.x, a.z, b.x, b.z);
                const int4* pt = (const int4*)((const long long*)ei + N_EDGES + e0);
                int4 cc = pt[0], dd = pt[1];
                tv = make_int4(cc.x, cc.z, dd.x, dd.z);
            } else {
                sv = *(const int4*)((const int*)ei + e0);
                tv = *(const int4*)((const int*)ei + N_EDGES + e0);
            }
            const float4 ev = *(const float4*)(eattr + e0);
            bucket_one(sv.x, tv.x, ev.x, recs, cnt, c);
            bucket_one(sv.y, tv.y, ev.y, recs, cnt, c);
            bucket_one(sv.z, tv.z, ev.z, recs, cnt, c);
            bucket_one(sv.w, tv.w, ev.w, recs, cnt, c);
        } else if (e0 < end) {
            for (int e = e0; e < end && e < e0 + 4; ++e) {
                int src, tgt;
                if (IS64) { src = (int)((const long long*)ei)[e]; tgt = (int)((const long long*)ei)[N_EDGES + e]; }
                else      { src = ((const int*)ei)[e];            tgt = ((const int*)ei)[N_EDGES + e]; }
                bucket_one(src, tgt, eattr[e], recs, cnt, c);
            }
        }
    }
}

__device__ __forceinline__ void node_body(const float* __restrict__ x,
                                          const float* __restrict__ Wl, const float* __restrict__ bl,
                                          const float* __restrict__ Wr, const float* __restrict__ br,
                                          float* __restrict__ xl, float* __restrict__ xr, int bid) {
    const int w    = bid * 4 + ((int)threadIdx.x >> 6);
    const int lane = threadIdx.x & 63;
    const int sub  = lane >> 4;
    const int l16  = lane & 15;
    const int n    = w * 4 + sub;             // < 100000 exactly
    float sl0 = 0.f, sl1 = 0.f, sr0 = 0.f, sr1 = 0.f;
    #pragma unroll
    for (int q = 0; q < 4; ++q) {
        const int k = q * 64 + l16 * 4;
        const float4 xv  = *(const float4*)(x + (size_t)n * D_IN + k);
        const float4 wlA = *(const float4*)(Wl + 2 * k);
        const float4 wlB = *(const float4*)(Wl + 2 * k + 4);
        const float4 wrA = *(const float4*)(Wr + 2 * k);
        const float4 wrB = *(const float4*)(Wr + 2 * k + 4);
        sl0 += xv.x*wlA.x + xv.y*wlA.z + xv.z*wlB.x + xv.w*wlB.z;
        sl1 += xv.x*wlA.y + xv.y*wlA.w + xv.z*wlB.y + xv.w*wlB.w;
        sr0 += xv.x*wrA.x + xv.y*wrA.z + xv.z*wrB.x + xv.w*wrB.z;
        sr1 += xv.x*wrA.y + xv.y*wrA.w + xv.z*wrB.y + xv.w*wrB.w;
    }
    #pragma unroll
    for (int o = 8; o > 0; o >>= 1) {
        sl0 += __shfl_xor(sl0, o);
        sl1 += __shfl_xor(sl1, o);
        sr0 += __shfl_xor(sr0, o);
        sr1 += __shfl_xor(sr1, o);
    }
    if (l16 == 0) {
        xl[2*n]   = sl0 + bl[0];
        xl[2*n+1] = sl1 + bl[1];
        xr[2*n]   = sr0 + br[0];
        xr[2*n+1] = sr1 + br[1];
    }
}

// Fused: blocks [0,NCH) bucket edges (LDS-atomic-pipe bound); blocks
// [NCH, NCH+NODE_BLKS) transform nodes (memory/VALU bound) — co-resident
// blocks overlap on different pipes.
__global__ __launch_bounds__(ABLK) void fused_node_bucket(
        const float* __restrict__ x,
        const float* __restrict__ Wl, const float* __restrict__ bl,
        const float* __restrict__ Wr, const float* __restrict__ br,
        const void* __restrict__ ei, const float* __restrict__ eattr,
        float* __restrict__ xl, float* __restrict__ xr,
        float2* __restrict__ recs, int* __restrict__ counts) {
    if (blockIdx.x < NCH) {
        __shared__ int cnt[NRSEG];
        __shared__ int sflag;
        const int c = blockIdx.x;
        if (threadIdx.x < NRSEG) cnt[threadIdx.x] = 0;
        if (threadIdx.x < 64) {   // wave 0: self-detect int64 vs int32
            int v = ((const int*)ei)[2 * threadIdx.x + 1];
            unsigned long long nz = __ballot(v != 0);
            if (threadIdx.x == 0) sflag = (nz == 0ull) ? 1 : 0;
        }
        __syncthreads();
        if (sflag) bucket_loop<true >(ei, eattr, recs, cnt, c);
        else       bucket_loop<false>(ei, eattr, recs, cnt, c);
        __syncthreads();
        if (threadIdx.x < NRSEG) {
            int v = cnt[threadIdx.x];
            counts[c * NRSEG + threadIdx.x] = v < CAP ? v : CAP;
        }
    } else {
        node_body(x, Wl, bl, Wr, br, xl, xr, (int)blockIdx.x - NCH);
    }
}

// Gather: block (r16, h, g) reads seg (chunk,r16) records, filters to half h,
// claim/winner LDS accumulation (75 KB -> 2 blocks/CU), dumps partial.
__global__ __launch_bounds__(CBLK, 8) void gather_accum(
        const float2* __restrict__ recs, const int* __restrict__ counts,
        const float* __restrict__ xl, const float* __restrict__ xr,
        const float* __restrict__ We, const float* __restrict__ att,
        float* __restrict__ partial) {
    __shared__ float  acc[RANGE * 3];   // 37.5 KB
    __shared__ float2 xrs[RANGE];       // 25 KB
    __shared__ int    tag[RANGE];       // 12.5 KB
    __shared__ int    s_n[CPG];
    const int b      = blockIdx.x;
    const int r16    = b & 15;
    const int h      = (b >> 4) & 1;
    const int g      = b >> 5;
    const int rr     = r16 * 2 + h;
    const int lo     = rr * RANGE;
    const int liBase = h * RANGE;
    for (int i = threadIdx.x; i < RANGE * 3; i += CBLK) acc[i] = 0.f;
    for (int i = threadIdx.x; i < RANGE; i += CBLK) xrs[i] = ((const float2*)xr)[lo + i];
    for (int i = threadIdx.x; i < CPG; i += CBLK) s_n[i] = counts[(g * CPG + i) * NRSEG + r16];
    __syncthreads();
    const float we0 = We[0], we1 = We[1];
    const float a0 = att[0], a1 = att[1];
    const float2* xl2 = (const float2*)xl;
    const int c0 = g * CPG;
    const int tid = threadIdx.x;

    // vm bit0/bit1: record exists (count) AND lands in this half-range
    auto fetch_pair = [&](int pidx, unsigned& vm) -> float4 {
        float4 out = make_float4(0.f, 0.f, 0.f, 0.f);
        vm = 0u;
        if (pidx < PFLAT) {
            const int cc = pidx / HALFCAP;
            const int i  = pidx - cc * HALFCAP;
            const int n  = s_n[cc];
            if (2 * i < n) {
                const float2* seg = recs + (size_t)((c0 + cc) * NRSEG + r16) * CAP;
                out = ((const float4*)seg)[i];
                unsigned v = 0u;
                if ((unsigned)((int)(__float_as_uint(out.x) >> 17) - liBase) < RANGE) v |= 1u;
                if ((2 * i + 1 < n) &&
                    (unsigned)((int)(__float_as_uint(out.z) >> 17) - liBase) < RANGE) v |= 2u;
                vm = v;
            }
        }
        return out;
    };

    unsigned vCur, vNxt, vFly;
    float4 curP = fetch_pair(tid, vCur);
    float4 nxtP = fetch_pair(CBLK + tid, vNxt);
    float2 xsA0 = make_float2(0.f, 0.f), xsA1 = make_float2(0.f, 0.f);
    if (vCur & 1u) xsA0 = xl2[__float_as_uint(curP.x) & 0x1FFFF];
    if (vCur & 2u) xsA1 = xl2[__float_as_uint(curP.z) & 0x1FFFF];

    bool d0 = false, d1 = false;
    int  dl0 = 0, dl1 = 0;
    float dc00 = 0.f, dc01 = 0.f, de0 = 0.f, dc10 = 0.f, dc11 = 0.f, de1 = 0.f;

    for (int bi = 0; bi < NB; ++bi) {
        float4 flyP = fetch_pair((bi + 2) * CBLK + tid, vFly);
        float2 xsB0 = make_float2(0.f, 0.f), xsB1 = make_float2(0.f, 0.f);
        if (vNxt & 1u) xsB0 = xl2[__float_as_uint(nxtP.x) & 0x1FFFF];
        if (vNxt & 2u) xsB1 = xl2[__float_as_uint(nxtP.z) & 0x1FFFF];

        // phase A: compute + claim; drain previous losers
        const bool h0 = (vCur & 1u) != 0u, h1 = (vCur & 2u) != 0u;
        int li0 = 0, li1 = 0;
        float ex0 = 0.f, cv00 = 0.f, cv01 = 0.f;
        float ex1 = 0.f, cv10 = 0.f, cv11 = 0.f;
        if (h0) {
            li0 = (int)(__float_as_uint(curP.x) >> 17) - liBase;
            const float2 xt = xrs[li0];
            float m0 = xsA0.x + xt.x + curP.y * we0;
            float m1 = xsA0.y + xt.y + curP.y * we1;
            m0 = m0 > 0.f ? m0 : NEG_SLOPE * m0;
            m1 = m1 > 0.f ? m1 : NEG_SLOPE * m1;
            ex0  = __expf(m0 * a0 + m1 * a1);
            cv00 = ex0 * xsA0.x;
            cv01 = ex0 * xsA0.y;
            tag[li0] = tid;
        }
        if (h1) {
            li1 = (int)(__float_as_uint(curP.z) >> 17) - liBase;
            const float2 xt = xrs[li1];
            float m0 = xsA1.x + xt.x + curP.w * we0;
            float m1 = xsA1.y + xt.y + curP.w * we1;
            m0 = m0 > 0.f ? m0 : NEG_SLOPE * m0;
            m1 = m1 > 0.f ? m1 : NEG_SLOPE * m1;
            ex1  = __expf(m0 * a0 + m1 * a1);
            cv10 = ex1 * xsA1.x;
            cv11 = ex1 * xsA1.y;
            tag[li1] = tid;
        }
        if (d0) {
            float* bp = acc + dl0 * 3;
            atomicAdd(bp + 0, dc00); atomicAdd(bp + 1, dc01); atomicAdd(bp + 2, de0);
            d0 = false;
        }
        if (d1) {
            float* bp = acc + dl1 * 3;
            atomicAdd(bp + 0, dc10); atomicAdd(bp + 1, dc11); atomicAdd(bp + 2, de1);
            d1 = false;
        }
        __syncthreads();
        // phase B: winners plain-RMW; losers deferred
        if (h0) {
            if (tag[li0] == tid) {
                float* bp = acc + li0 * 3;
                bp[0] += cv00; bp[1] += cv01; bp[2] += ex0;
            } else { d0 = true; dl0 = li0; dc00 = cv00; dc01 = cv01; de0 = ex0; }
        }
        if (h1) {
            if (tag[li1] == tid) {
                float* bp = acc + li1 * 3;
                bp[0] += cv10; bp[1] += cv11; bp[2] += ex1;
            } else { d1 = true; dl1 = li1; dc10 = cv10; dc11 = cv11; de1 = ex1; }
        }
        __syncthreads();
        curP = nxtP; vCur = vNxt; xsA0 = xsB0; xsA1 = xsB1;
        nxtP = flyP; vNxt = vFly;
    }
    if (d0) {
        float* bp = acc + dl0 * 3;
        atomicAdd(bp + 0, dc00); atomicAdd(bp + 1, dc01); atomicAdd(bp + 2, de0);
    }
    if (d1) {
        float* bp = acc + dl1 * 3;
        atomicAdd(bp + 0, dc10); atomicAdd(bp + 1, dc11); atomicAdd(bp + 2, de1);
    }
    __syncthreads();

    float* dst = partial + (size_t)(rr * NG + g) * (RANGE * 3);
    for (int i = threadIdx.x; i < RANGE * 3; i += CBLK) dst[i] = acc[i];
}

// Sum the NG partials per node, normalize, add bias.
__global__ void reduce_partials(const float* __restrict__ partial,
                                const float* __restrict__ bias, float* __restrict__ out) {
    int i = blockIdx.x * blockDim.x + threadIdx.x;
    if (i >= N_NODES) return;
    const int r = i / RANGE;
    const int li = i - r * RANGE;
    float n0 = 0.f, n1 = 0.f, d = 0.f;
    #pragma unroll 4
    for (int g = 0; g < NG; ++g) {
        const float* p = partial + (size_t)(r * NG + g) * (RANGE * 3) + (size_t)li * 3;
        n0 += p[0]; n1 += p[1]; d += p[2];
    }
    d += 1e-16f;
    float2 o;
    o.x = n0 / d + bias[0];
    o.y = n1 / d + bias[1];
    ((float2*)out)[i] = o;
}

// ---------------- fallbacks (small ws) ----------------
__global__ __launch_bounds__(ABLK) void node_only(const float* __restrict__ x,
                                                  const float* __restrict__ Wl, const float* __restrict__ bl,
                                                  const float* __restrict__ Wr, const float* __restrict__ br,
                                                  float* __restrict__ xl, float* __restrict__ xr) {
    node_body(x, Wl, bl, Wr, br, xl, xr, (int)blockIdx.x);
}

__global__ void detect_dtype(const int* __restrict__ ei32, int* __restrict__ flag) {
    int lane = threadIdx.x;
    int v = ei32[2 * lane + 1];
    unsigned long long nz = __ballot(v != 0);
    if (lane == 0) *flag = (nz == 0ull) ? 1 : 0;
}

template <bool IS64>
__device__ __forceinline__ void scan_loop(const void* __restrict__ ei,
                                          const float* __restrict__ eattr,
                                          const float2* __restrict__ xl2,
                                          const float2* __restrict__ xr2,
                                          float we0, float we1, float a0, float a1,
                                          int lo, int eBeg, int eEnd,
                                          float* __restrict__ acc) {
    for (int e = eBeg + (int)threadIdx.x; e < eEnd; e += CBLK) {
        int tgt;
        if (IS64) tgt = (int)((const long long*)ei)[N_EDGES + e];
        else      tgt = ((const int*)ei)[N_EDGES + e];
        unsigned li = (unsigned)(tgt - lo);
        if (li < RANGE) {
            int src;
            if (IS64) src = (int)((const long long*)ei)[e];
            else      src = ((const int*)ei)[e];
            const float ea = eattr[e];
            const float2 xs = xl2[src];
            const float2 xt = xr2[tgt];
            float m0 = xs.x + xt.x + ea * we0;
            float m1 = xs.y + xt.y + ea * we1;
            m0 = m0 > 0.f ? m0 : NEG_SLOPE * m0;
            m1 = m1 > 0.f ? m1 : NEG_SLOPE * m1;
            const float ex = __expf(m0 * a0 + m1 * a1);
            float* b = acc + li * 3u;
            atomicAdd(b + 0, ex * xs.x);
            atomicAdd(b + 1, ex * xs.y);
            atomicAdd(b + 2, ex);
        }
    }
}

__global__ __launch_bounds__(CBLK) void edge_scan(const void* __restrict__ ei,
                                                  const float* __restrict__ eattr,
                                                  const float* __restrict__ xl,
                                                  const float* __restrict__ xr,
                                                  const float* __restrict__ We,
                                                  const float* __restrict__ att,
                                                  float* __restrict__ partial,
                                                  const int* __restrict__ flag) {
    __shared__ float acc[RANGE * 3];
    const int r = blockIdx.x & (NRANGES - 1);
    const int g = blockIdx.x >> 5;
    for (int i = threadIdx.x; i < RANGE * 3; i += CBLK) acc[i] = 0.f;
    __syncthreads();
    const int lo = r * RANGE;
    const int eBeg = g * FCHE, eEnd = eBeg + FCHE;
    const float we0 = We[0], we1 = We[1];
    const float a0 = att[0], a1 = att[1];
    if (*flag)
        scan_loop<true >(ei, eattr, (const float2*)xl, (const float2*)xr, we0, we1, a0, a1, lo, eBeg, eEnd, acc);
    else
        scan_loop<false>(ei, eattr, (const float2*)xl, (const float2*)xr, we0, we1, a0, a1, lo, eBeg, eEnd, acc);
    __syncthreads();
    float* dst = partial + (size_t)(r * NG + g) * (RANGE * 3);
    for (int i = threadIdx.x; i < RANGE * 3; i += CBLK) dst[i] = acc[i];
}

__global__ void edge_pass_atomic(const void* __restrict__ ei,
                                 const float* __restrict__ eattr,
                                 const float* __restrict__ xl, const float* __restrict__ xr,
                                 const float* __restrict__ We, const float* __restrict__ att,
                                 float* __restrict__ acc4, const int* __restrict__ flag) {
    const int is64 = *flag;
    const float we0 = We[0], we1 = We[1];
    const float a0 = att[0], a1 = att[1];
    const int stride = gridDim.x * blockDim.x;
    for (int e = blockIdx.x * blockDim.x + threadIdx.x; e < N_EDGES; e += stride) {
        int src, tgt;
        if (is64) { src = (int)((const long long*)ei)[e]; tgt = (int)((const long long*)ei)[N_EDGES + e]; }
        else      { src = ((const int*)ei)[e];            tgt = ((const int*)ei)[N_EDGES + e]; }
        const float ea = eattr[e];
        const float2 xs = ((const float2*)xl)[src];
        const float2 xt = ((const float2*)xr)[tgt];
        float m0 = xs.x + xt.x + ea * we0;
        float m1 = xs.y + xt.y + ea * we1;
        m0 = m0 > 0.f ? m0 : NEG_SLOPE * m0;
        m1 = m1 > 0.f ? m1 : NEG_SLOPE * m1;
        const float ex = __expf(m0 * a0 + m1 * a1);
        float* b = acc4 + (size_t)tgt * 4;
        atomicAdd(b + 0, ex * xs.x);
        atomicAdd(b + 1, ex * xs.y);
        atomicAdd(b + 2, ex);
    }
}

__global__ void finalize4(const float* __restrict__ acc4,
                          const float* __restrict__ bias, float* __restrict__ out) {
    int i = blockIdx.x * blockDim.x + threadIdx.x;
    if (i >= N_NODES) return;
    const float4 a = ((const float4*)acc4)[i];
    const float d = a.z + 1e-16f;
    float2 o;
    o.x = a.x / d + bias[0];
    o.y = a.y / d + bias[1];
    ((float2*)out)[i] = o;
}
// -------------------------------------------------------

extern "C" void kernel_launch(void* const* d_in, const int* in_sizes, int n_in,
                              void* d_out, int out_size, void* d_ws, size_t ws_size,
                              hipStream_t stream) {
    const float* x    = (const float*)d_in[0];
    const void*  ei   = d_in[1];
    const float* ea   = (const float*)d_in[2];
    const float* Wl   = (const float*)d_in[3];
    const float* bl   = (const float*)d_in[4];
    const float* Wr   = (const float*)d_in[5];
    const float* br   = (const float*)d_in[6];
    const float* We   = (const float*)d_in[7];
    const float* att  = (const float*)d_in[8];
    const float* bias = (const float*)d_in[9];

    float* ws      = (float*)d_ws;
    float* xl      = ws;
    float* xr      = ws + 2 * N_NODES;
    float* partial = ws + 4 * N_NODES;
    const size_t partial_floats = (size_t)NRANGES * NG * RANGE * 3;
    float* recs_f  = partial + partial_floats;                 // [NCH*NRSEG][CAP] float2
    const size_t recs_floats = (size_t)NCH * NRSEG * CAP * 2;
    int*   counts  = (int*)(recs_f + recs_floats);             // [NCH*NRSEG]

    const size_t need_bucket = (4 * (size_t)N_NODES + partial_floats + recs_floats
                                + (size_t)NCH * NRSEG + 16) * sizeof(float);
    const size_t need_scan   = (4 * (size_t)N_NODES + partial_floats + 16) * sizeof(float);

    if (ws_size >= need_bucket) {
        fused_node_bucket<<<NCH + NODE_BLKS, ABLK, 0, stream>>>(
            x, Wl, bl, Wr, br, ei, ea, xl, xr, (float2*)recs_f, counts);
        gather_accum<<<NRANGES * NG, CBLK, 0, stream>>>(
            (const float2*)recs_f, counts, xl, xr, We, att, partial);
        reduce_partials<<<(N_NODES + 255) / 256, 256, 0, stream>>>(partial, bias, (float*)d_out);
    } else if (ws_size >= need_scan) {
        int* f2 = (int*)(partial + partial_floats);
        node_only<<<NODE_BLKS, ABLK, 0, stream>>>(x, Wl, bl, Wr, br, xl, xr);
        detect_dtype<<<1, 64, 0, stream>>>((const int*)ei, f2);
        edge_scan<<<NRANGES * NG, CBLK, 0, stream>>>(ei, ea, xl, xr, We, att, partial, f2);
        reduce_partials<<<(N_NODES + 255) / 256, 256, 0, stream>>>(partial, bias, (float*)d_out);
    } else {
        float* acc4 = ws + 4 * N_NODES;
        int* f3 = (int*)(acc4 + 4 * (size_t)N_NODES);
        hipMemsetAsync(acc4, 0, (size_t)N_NODES * 4 * sizeof(float), stream);
        node_only<<<NODE_BLKS, ABLK, 0, stream>>>(x, Wl, bl, Wr, br, xl, xr);
        detect_dtype<<<1, 64, 0, stream>>>((const int*)ei, f3);
        edge_pass_atomic<<<4096, 256, 0, stream>>>(ei, ea, xl, xr, We, att, acc4, f3);
        finalize4<<<(N_NODES + 255) / 256, 256, 0, stream>>>(acc4, bias, (float*)d_out);
    }
}